// Round 2
// baseline (8036.159 us; speedup 1.0000x reference)
//
#include <hip/hip_runtime.h>
#include <math.h>

#define Bsz  8192
#define Mdim 512
#define Ndim 2048
#define Kit  16
#define Pk   50
#define EPSv 0.01f

// ---------------------------------------------------------------------------
// GEMM1 (NT, split-K): part[ks][r,m] = sum_{k in ks-range} z[r,k] * A[m,k]
// tile 128x128, BK=16, 256 thr, micro 8x(4+4), global->reg prefetch
// ---------------------------------------------------------------------------
__global__ __launch_bounds__(256) void gemm1_kernel(
    const float* __restrict__ z, const float* __restrict__ A,
    float* __restrict__ part, int klen)
{
    const int tid = threadIdx.x;
    const int tx  = tid & 15;
    const int ty  = tid >> 4;
    const int m0  = blockIdx.x * 128;
    const int r0  = blockIdx.y * 128;
    const int kstart = blockIdx.z * klen;
    part += (size_t)blockIdx.z * Bsz * Mdim;

    __shared__ float zt[16][132];   // [k][row]
    __shared__ float at[16][132];   // [k][m]

    float acc[8][8];
#pragma unroll
    for (int i = 0; i < 8; i++)
#pragma unroll
        for (int j = 0; j < 8; j++) acc[i][j] = 0.f;

    // staging map: f = tid (+256): row = f>>2 (0..63, +64), kk = (f&3)*4
    const int srow = tid >> 2;
    const int skk  = (tid & 3) << 2;
    const float* zp0 = z + (size_t)(r0 + srow)      * Ndim + skk;
    const float* zp1 = z + (size_t)(r0 + srow + 64) * Ndim + skk;
    const float* ap0 = A + (size_t)(m0 + srow)      * Ndim + skk;
    const float* ap1 = A + (size_t)(m0 + srow + 64) * Ndim + skk;

    const int kend = kstart + klen;
    int k0 = kstart;
    float4 zr0 = *(const float4*)(zp0 + k0);
    float4 zr1 = *(const float4*)(zp1 + k0);
    float4 ar0 = *(const float4*)(ap0 + k0);
    float4 ar1 = *(const float4*)(ap1 + k0);

    for (; k0 < kend; k0 += 16) {
        __syncthreads();
        zt[skk + 0][srow] = zr0.x; zt[skk + 1][srow] = zr0.y;
        zt[skk + 2][srow] = zr0.z; zt[skk + 3][srow] = zr0.w;
        zt[skk + 0][srow + 64] = zr1.x; zt[skk + 1][srow + 64] = zr1.y;
        zt[skk + 2][srow + 64] = zr1.z; zt[skk + 3][srow + 64] = zr1.w;
        at[skk + 0][srow] = ar0.x; at[skk + 1][srow] = ar0.y;
        at[skk + 2][srow] = ar0.z; at[skk + 3][srow] = ar0.w;
        at[skk + 0][srow + 64] = ar1.x; at[skk + 1][srow + 64] = ar1.y;
        at[skk + 2][srow + 64] = ar1.z; at[skk + 3][srow + 64] = ar1.w;
        __syncthreads();
        if (k0 + 16 < kend) {
            zr0 = *(const float4*)(zp0 + k0 + 16);
            zr1 = *(const float4*)(zp1 + k0 + 16);
            ar0 = *(const float4*)(ap0 + k0 + 16);
            ar1 = *(const float4*)(ap1 + k0 + 16);
        }
#pragma unroll
        for (int k = 0; k < 16; ++k) {
            float4 z0 = *(const float4*)&zt[k][ty * 8];
            float4 z1 = *(const float4*)&zt[k][ty * 8 + 4];
            float4 a0 = *(const float4*)&at[k][tx * 4];
            float4 a1 = *(const float4*)&at[k][tx * 4 + 64];
            float zr[8] = { z0.x, z0.y, z0.z, z0.w, z1.x, z1.y, z1.z, z1.w };
            float arr[8] = { a0.x, a0.y, a0.z, a0.w, a1.x, a1.y, a1.z, a1.w };
#pragma unroll
            for (int i = 0; i < 8; i++)
#pragma unroll
                for (int j = 0; j < 8; j++)
                    acc[i][j] = fmaf(zr[i], arr[j], acc[i][j]);
        }
    }
#pragma unroll
    for (int i = 0; i < 8; i++) {
        size_t base = (size_t)(r0 + ty * 8 + i) * Mdim + m0;
        float4 o0 = { acc[i][0], acc[i][1], acc[i][2], acc[i][3] };
        float4 o1 = { acc[i][4], acc[i][5], acc[i][6], acc[i][7] };
        *(float4*)(part + base + tx * 4)      = o0;
        *(float4*)(part + base + 64 + tx * 4) = o1;
    }
}

// ---------------------------------------------------------------------------
// GEMM2 (NN): u[B,N] = x - gamma * (b @ A),  b staged on the fly as
// b = (p0?p0:0) + (p1?p1:0) - y   (p0==p1==null at iter 0 -> b = -y)
// tile 128x128, BK=16, 256 thr, micro 8x(4+4), global->reg prefetch
// ---------------------------------------------------------------------------
__global__ __launch_bounds__(256) void gemm2_kernel(
    const float* __restrict__ p0, const float* __restrict__ p1,
    const float* __restrict__ y,  const float* __restrict__ A,
    const float* __restrict__ x,  const float* __restrict__ gamma,
    int it, float* __restrict__ u)
{
    const int tid = threadIdx.x;
    const int tx  = tid & 15;
    const int ty  = tid >> 4;
    const int n0  = blockIdx.x * 128;
    const int r0  = blockIdx.y * 128;
    const float g = gamma[it];

    __shared__ float bt[16][132];   // [k][row]
    __shared__ float at[16][132];   // [k][n]

    float acc[8][8];
#pragma unroll
    for (int i = 0; i < 8; i++)
#pragma unroll
        for (int j = 0; j < 8; j++) acc[i][j] = 0.f;

    // bt staging map: row = tid>>2 (+64), kk = (tid&3)*4
    const int srow = tid >> 2;
    const int skk  = (tid & 3) << 2;
    const size_t boff0 = (size_t)(r0 + srow) * Mdim + skk;
    const size_t boff1 = boff0 + (size_t)64 * Mdim;
    // at staging map: m = tid>>5 (+8), nn = (tid&31)*4
    const int sm = tid >> 5;
    const int sn = (tid & 31) << 2;
    const float* apA = A + (size_t)sm * Ndim + n0 + sn;

    auto loadB = [&](size_t off) -> float4 {
        float4 t = *(const float4*)(y + off);
        float4 r = { -t.x, -t.y, -t.z, -t.w };
        if (p0) {
            float4 q = *(const float4*)(p0 + off);
            r.x += q.x; r.y += q.y; r.z += q.z; r.w += q.w;
        }
        if (p1) {
            float4 q = *(const float4*)(p1 + off);
            r.x += q.x; r.y += q.y; r.z += q.z; r.w += q.w;
        }
        return r;
    };

    int k0 = 0;
    float4 br0 = loadB(boff0 + k0);
    float4 br1 = loadB(boff1 + k0);
    float4 ar0 = *(const float4*)(apA + (size_t)k0 * Ndim);
    float4 ar1 = *(const float4*)(apA + (size_t)(k0 + 8) * Ndim);

    for (; k0 < Mdim; k0 += 16) {
        __syncthreads();
        bt[skk + 0][srow] = br0.x; bt[skk + 1][srow] = br0.y;
        bt[skk + 2][srow] = br0.z; bt[skk + 3][srow] = br0.w;
        bt[skk + 0][srow + 64] = br1.x; bt[skk + 1][srow + 64] = br1.y;
        bt[skk + 2][srow + 64] = br1.z; bt[skk + 3][srow + 64] = br1.w;
        *(float4*)&at[sm][sn]     = ar0;
        *(float4*)&at[sm + 8][sn] = ar1;
        __syncthreads();
        if (k0 + 16 < Mdim) {
            br0 = loadB(boff0 + k0 + 16);
            br1 = loadB(boff1 + k0 + 16);
            ar0 = *(const float4*)(apA + (size_t)(k0 + 16) * Ndim);
            ar1 = *(const float4*)(apA + (size_t)(k0 + 24) * Ndim);
        }
#pragma unroll
        for (int k = 0; k < 16; ++k) {
            float4 b0 = *(const float4*)&bt[k][ty * 8];
            float4 b1 = *(const float4*)&bt[k][ty * 8 + 4];
            float4 a0 = *(const float4*)&at[k][tx * 4];
            float4 a1 = *(const float4*)&at[k][tx * 4 + 64];
            float br[8] = { b0.x, b0.y, b0.z, b0.w, b1.x, b1.y, b1.z, b1.w };
            float ar[8] = { a0.x, a0.y, a0.z, a0.w, a1.x, a1.y, a1.z, a1.w };
#pragma unroll
            for (int i = 0; i < 8; i++)
#pragma unroll
                for (int j = 0; j < 8; j++)
                    acc[i][j] = fmaf(br[i], ar[j], acc[i][j]);
        }
    }
#pragma unroll
    for (int i = 0; i < 8; i++) {
        size_t base = (size_t)(r0 + ty * 8 + i) * Ndim + n0;
        float4 x0 = *(const float4*)(x + base + tx * 4);
        float4 x1 = *(const float4*)(x + base + 64 + tx * 4);
        float4 o0, o1;
        o0.x = x0.x - g * acc[i][0]; o0.y = x0.y - g * acc[i][1];
        o0.z = x0.z - g * acc[i][2]; o0.w = x0.w - g * acc[i][3];
        o1.x = x1.x - g * acc[i][4]; o1.y = x1.y - g * acc[i][5];
        o1.z = x1.z - g * acc[i][6]; o1.w = x1.w - g * acc[i][7];
        *(float4*)(u + base + tx * 4)      = o0;
        *(float4*)(u + base + 64 + tx * 4) = o1;
    }
}

// ---------------------------------------------------------------------------
// Fused per-row: exact 50th-largest |u| via 4-pass radix select (single-wave
// suffix scan), soft-threshold + overshoot update of x, z = gain_{it+1}*x_new.
// One block (256 thr) per row; u and z share the buffer.
// ---------------------------------------------------------------------------
__global__ __launch_bounds__(256) void topk_update_kernel(
    float* __restrict__ uz, float* __restrict__ x,
    const float* __restrict__ theta, const float* __restrict__ a_param,
    const float* __restrict__ vv, const float* __restrict__ vu, int it) {
    const int row = blockIdx.x;
    const int t   = threadIdx.x;
    float* urow = uz + (size_t)row * Ndim;
    float* xrow = x  + (size_t)row * Ndim;

    float4 u0 = *(const float4*)(urow + 4 * t);
    float4 u1 = *(const float4*)(urow + 4 * t + 1024);
    float uvals[8] = { u0.x, u0.y, u0.z, u0.w, u1.x, u1.y, u1.z, u1.w };
    unsigned keys[8];
#pragma unroll
    for (int e = 0; e < 8; e++) keys[e] = __float_as_uint(fabsf(uvals[e]));

    __shared__ unsigned bins[256];
    __shared__ unsigned sel[2];

    unsigned prefix = 0;
    unsigned k = Pk;
#pragma unroll
    for (int pass = 0; pass < 4; ++pass) {
        const int shift = 24 - pass * 8;
        bins[t] = 0;
        __syncthreads();
        const unsigned himask = (pass == 0) ? 0u : (0xFFFFFFFFu << (shift + 8));
#pragma unroll
        for (int e = 0; e < 8; e++) {
            if ((keys[e] & himask) == prefix)
                atomicAdd(&bins[(keys[e] >> shift) & 255], 1u);
        }
        __syncthreads();
        if (t < 64) {
            const int i0 = 255 - 4 * t;          // descending bins i0..i0-3
            unsigned c0 = bins[i0], c1 = bins[i0 - 1];
            unsigned c2 = bins[i0 - 2], c3 = bins[i0 - 3];
            unsigned s = c0 + c1 + c2 + c3;
            unsigned sc = s;
#pragma unroll
            for (int off = 1; off < 64; off <<= 1) {
                unsigned o = __shfl_up(sc, (unsigned)off);
                if (t >= off) sc += o;
            }
            unsigned pre = sc - s;               // count in strictly-higher bins
            unsigned cs[4] = { c0, c1, c2, c3 };
#pragma unroll
            for (int j = 0; j < 4; j++) {
                unsigned c = cs[j];
                if (pre < k && pre + c >= k) { sel[0] = (unsigned)(i0 - j); sel[1] = k - pre; }
                pre += c;
            }
        }
        __syncthreads();
        prefix |= sel[0] << shift;
        k = sel[1];
    }
    const float thresh = __uint_as_float(prefix);   // exact 50th-largest |u|

    const float th = theta[it];
    const float ap = a_param[it];
    const bool haveNext = (it + 1) < Kit;
    float tn = 0.f, vn = 0.f, vun = 0.f;
    if (haveNext) { tn = theta[it + 1]; vn = vv[it + 1]; vun = vu[it + 1]; }

    float4 x0 = *(const float4*)(xrow + 4 * t);
    float4 x1 = *(const float4*)(xrow + 4 * t + 1024);
    float xv[8] = { x0.x, x0.y, x0.z, x0.w, x1.x, x1.y, x1.z, x1.w };

    float xo[8], zo[8];
#pragma unroll
    for (int e = 0; e < 8; e++) {
        float uval = uvals[e];
        float au   = fabsf(uval);
        bool keep  = au > thresh;                  // strict, matches jax
        float shr  = copysignf(fmaxf(au - th, 0.f), uval);
        float xn   = keep ? uval : shr;
        float d    = xn - xv[e];
        float ov   = 1.f + ap / (fabsf(d) + EPSv);
        float xr   = xv[e] + ov * d;
        xo[e] = xr;
        zo[e] = (1.f + tn * vun * __expf(-vn * fabsf(xr))) * xr;
    }
    float4 a0 = { xo[0], xo[1], xo[2], xo[3] };
    float4 a1 = { xo[4], xo[5], xo[6], xo[7] };
    *(float4*)(xrow + 4 * t) = a0;
    *(float4*)(xrow + 4 * t + 1024) = a1;
    if (haveNext) {
        float4 z0 = { zo[0], zo[1], zo[2], zo[3] };
        float4 z1 = { zo[4], zo[5], zo[6], zo[7] };
        *(float4*)(urow + 4 * t) = z0;
        *(float4*)(urow + 4 * t + 1024) = z1;
    }
}

// ---------------------------------------------------------------------------
extern "C" void kernel_launch(void* const* d_in, const int* in_sizes, int n_in,
                              void* d_out, int out_size, void* d_ws, size_t ws_size,
                              hipStream_t stream) {
    const float* y       = (const float*)d_in[0];   // (B,M)
    const float* A       = (const float*)d_in[1];   // (M,N)
    const float* gamma   = (const float*)d_in[2];   // (K)
    const float* theta   = (const float*)d_in[3];   // (K)
    const float* a_param = (const float*)d_in[4];   // (K)
    const float* v       = (const float*)d_in[5];   // (K)
    const float* vu      = (const float*)d_in[6];   // (K)
    // d_in[7] = theta_init (only multiplies x==0 at iter 0 -> unused)
    // d_in[8] = info (unused)

    float* x  = (float*)d_out;                      // (B,N) + 2K tail zeros
    float* uz = (float*)d_ws;                       // (B,N)  u / z shared
    float* p0 = uz + (size_t)Bsz * Ndim;            // (B,M) partial 0

    const size_t need2 = ((size_t)Bsz * Ndim + 2 * (size_t)Bsz * Mdim) * sizeof(float);
    const int ksplit = (ws_size >= need2) ? 2 : 1;
    float* p1 = (ksplit == 2) ? (p0 + (size_t)Bsz * Mdim) : nullptr;

    hipMemsetAsync(d_out, 0, (size_t)out_size * sizeof(float), stream);

    dim3 blk(256);
    dim3 g1(Mdim / 128, Bsz / 128, ksplit);
    dim3 g2(Ndim / 128, Bsz / 128);

    for (int it = 0; it < Kit; ++it) {
        if (it > 0)
            gemm1_kernel<<<g1, blk, 0, stream>>>(uz, A, p0, Ndim / ksplit);
        gemm2_kernel<<<g2, blk, 0, stream>>>(it == 0 ? nullptr : p0,
                                             it == 0 ? nullptr : p1,
                                             y, A, x, gamma, it, uz);
        topk_update_kernel<<<Bsz, blk, 0, stream>>>(uz, x, theta, a_param, v, vu, it);
    }
}

// Round 3
// 4854.877 us; speedup vs baseline: 1.6553x; 1.6553x over previous
//
#include <hip/hip_runtime.h>
#include <math.h>

#define Bsz  8192
#define Mdim 512
#define Ndim 2048
#define Kit  16
#define Pk   50
#define EPSv 0.01f

typedef __attribute__((ext_vector_type(8))) short bf16x8;
typedef __attribute__((ext_vector_type(4))) float f32x4;

// ---- bf16 split helpers: x = h + l exactly to ~2^-16 rel --------------------
static __device__ __forceinline__ unsigned short f2bf(float f) {
    unsigned u = __float_as_uint(f);
    return (unsigned short)((u + 0x7fffu + ((u >> 16) & 1u)) >> 16);  // RNE
}
static __device__ __forceinline__ float bf2f(unsigned short h) {
    return __uint_as_float(((unsigned)h) << 16);
}
static __device__ __forceinline__ unsigned packsplit(float x) {
    unsigned short h = f2bf(x);
    float l = x - bf2f(h);          // exact in fp32
    unsigned short lo = f2bf(l);
    return (unsigned)h | ((unsigned)lo << 16);
}
static __device__ __forceinline__ void unpack8(const unsigned* p, bf16x8& h, bf16x8& l) {
#pragma unroll
    for (int j = 0; j < 8; j++) {
        h[j] = (short)(p[j] & 0xffffu);
        l[j] = (short)(p[j] >> 16);
    }
}

// ---------------------------------------------------------------------------
// it=0: b = -y, stored packed-split.
// ---------------------------------------------------------------------------
__global__ __launch_bounds__(256) void split_negy_kernel(const float* __restrict__ y,
                                                         unsigned* __restrict__ bpk) {
    int i = blockIdx.x * 256 + threadIdx.x;            // float4 index
    float4 v = ((const float4*)y)[i];
    uint4 o = { packsplit(-v.x), packsplit(-v.y), packsplit(-v.z), packsplit(-v.w) };
    ((uint4*)bpk)[i] = o;
}

// ---------------------------------------------------------------------------
// GEMM1 (NT): b[r][m] = sum_n z[r][n]*A[m][n] - y[r][m], output packed-split.
// z packed (B,N). MFMA 16x16x32 bf16, 3-product split. Tile 128(r)x64(m), BK=32.
// ---------------------------------------------------------------------------
__global__ __launch_bounds__(256) void gemm1_mfma(
    const unsigned* __restrict__ zpk, const float* __restrict__ A,
    const float* __restrict__ y, unsigned* __restrict__ bpk)
{
    const int tid  = threadIdx.x;
    const int lane = tid & 63, wid = tid >> 6;
    const int lm   = lane & 15, quad = lane >> 4;
    const int wr   = (wid & 1) * 64, wm = (wid >> 1) * 32;
    const int m0   = blockIdx.x * 64, r0 = blockIdx.y * 128;

    __shared__ unsigned zb[128][36];   // z tile packed [row][k], stride 144B (2-way reads)
    __shared__ unsigned ap[64][36];    // A tile packed [m][k]

    f32x4 acc[4][2];
#pragma unroll
    for (int i = 0; i < 4; i++)
#pragma unroll
        for (int j = 0; j < 2; j++) acc[i][j] = (f32x4)0.f;

    const int srow = tid >> 3;         // 0..31
    const int sq   = tid & 7;          // 16B segment within 128B row
    const unsigned* zbase = zpk + (size_t)(r0 + srow) * Ndim + sq * 4;
    const float*    abase = A   + (size_t)(m0 + srow) * Ndim + sq * 4;

    uint4  pz[4];
    float4 pa[2];
#pragma unroll
    for (int s = 0; s < 4; s++) pz[s] = *(const uint4*)(zbase + (size_t)(32 * s) * Ndim);
#pragma unroll
    for (int s = 0; s < 2; s++) pa[s] = *(const float4*)(abase + (size_t)(32 * s) * Ndim);

    for (int k0 = 0; k0 < Ndim; k0 += 32) {
        __syncthreads();
#pragma unroll
        for (int s = 0; s < 4; s++) *(uint4*)&zb[srow + 32 * s][sq * 4] = pz[s];
#pragma unroll
        for (int s = 0; s < 2; s++) {
            float4 v = pa[s];
            uint4 w = { packsplit(v.x), packsplit(v.y), packsplit(v.z), packsplit(v.w) };
            *(uint4*)&ap[srow + 32 * s][sq * 4] = w;
        }
        __syncthreads();
        if (k0 + 32 < Ndim) {
#pragma unroll
            for (int s = 0; s < 4; s++)
                pz[s] = *(const uint4*)(zbase + (size_t)(32 * s) * Ndim + k0 + 32);
#pragma unroll
            for (int s = 0; s < 2; s++)
                pa[s] = *(const float4*)(abase + (size_t)(32 * s) * Ndim + k0 + 32);
        }
        // B-operand frags (A): 2 m-positions
        bf16x8 bh[2], bl[2];
#pragma unroll
        for (int fj = 0; fj < 2; fj++) {
            int mc = wm + fj * 16 + lm;
            unsigned pp[8];
            *(uint4*)&pp[0] = *(const uint4*)&ap[mc][quad * 8];
            *(uint4*)&pp[4] = *(const uint4*)&ap[mc][quad * 8 + 4];
            unpack8(pp, bh[fj], bl[fj]);
        }
#pragma unroll
        for (int fi = 0; fi < 4; fi++) {
            int rr = wr + fi * 16 + lm;
            unsigned pp[8];
            *(uint4*)&pp[0] = *(const uint4*)&zb[rr][quad * 8];
            *(uint4*)&pp[4] = *(const uint4*)&zb[rr][quad * 8 + 4];
            bf16x8 zh, zl;
            unpack8(pp, zh, zl);
#pragma unroll
            for (int fj = 0; fj < 2; fj++) {
                acc[fi][fj] = __builtin_amdgcn_mfma_f32_16x16x32_bf16(zh, bh[fj], acc[fi][fj], 0, 0, 0);
                acc[fi][fj] = __builtin_amdgcn_mfma_f32_16x16x32_bf16(zh, bl[fj], acc[fi][fj], 0, 0, 0);
                acc[fi][fj] = __builtin_amdgcn_mfma_f32_16x16x32_bf16(zl, bh[fj], acc[fi][fj], 0, 0, 0);
            }
        }
    }
    // epilogue: subtract y, split, store packed.  D[m=quad*4+r][n=lm]
#pragma unroll
    for (int fi = 0; fi < 4; fi++)
#pragma unroll
        for (int fj = 0; fj < 2; fj++)
#pragma unroll
            for (int r = 0; r < 4; r++) {
                int row = r0 + wr + fi * 16 + quad * 4 + r;
                int col = m0 + wm + fj * 16 + lm;
                float bv = acc[fi][fj][r] - y[(size_t)row * Mdim + col];
                bpk[(size_t)row * Mdim + col] = packsplit(bv);
            }
}

// ---------------------------------------------------------------------------
// GEMM2 (NN): c[r][n] = sum_m b[r][m]*A[m][n], c fp32. b packed (B,M).
// A transposed+split in-kernel into packed [n][k] LDS tile. Tile 128x128, BK=32.
// ---------------------------------------------------------------------------
__global__ __launch_bounds__(256) void gemm2_mfma(
    const unsigned* __restrict__ bpk, const float* __restrict__ A,
    float* __restrict__ c)
{
    const int tid  = threadIdx.x;
    const int lane = tid & 63, wid = tid >> 6;
    const int lm   = lane & 15, quad = lane >> 4;
    const int wr   = (wid & 1) * 64, wn = (wid >> 1) * 64;
    const int n0   = blockIdx.x * 128, r0 = blockIdx.y * 128;

    __shared__ unsigned zb[128][36];   // b tile packed [row][k=m]
    __shared__ unsigned ap[128][36];   // A tile packed [n][k=m]

    f32x4 acc[4][4];
#pragma unroll
    for (int i = 0; i < 4; i++)
#pragma unroll
        for (int j = 0; j < 4; j++) acc[i][j] = (f32x4)0.f;

    // b staging: row = (tid>>3)+32s, 16B seg q = tid&7
    const int srow = tid >> 3;
    const int sq   = tid & 7;
    const unsigned* bbase = bpk + (size_t)(r0 + srow) * Mdim + sq * 4;
    // A staging (transpose): nb = tid&31, mrow = tid>>5 (0..7); m = mrow+8s; n = nb+32e
    const int nb = tid & 31, mrow = tid >> 5;
    const float* abase = A + (size_t)mrow * Ndim + n0 + nb;

    uint4 pb[4];
    float pav[4][4];
#pragma unroll
    for (int s = 0; s < 4; s++) pb[s] = *(const uint4*)(bbase + (size_t)(32 * s) * Mdim);
#pragma unroll
    for (int s = 0; s < 4; s++) {
        const float* ar = abase + (size_t)(8 * s) * Ndim;
#pragma unroll
        for (int e = 0; e < 4; e++) pav[s][e] = ar[32 * e];
    }

    for (int k0 = 0; k0 < Mdim; k0 += 32) {
        __syncthreads();
#pragma unroll
        for (int s = 0; s < 4; s++) *(uint4*)&zb[srow + 32 * s][sq * 4] = pb[s];
#pragma unroll
        for (int s = 0; s < 4; s++)
#pragma unroll
            for (int e = 0; e < 4; e++)
                ap[nb + 32 * e][mrow + 8 * s] = packsplit(pav[s][e]);
        __syncthreads();
        if (k0 + 32 < Mdim) {
#pragma unroll
            for (int s = 0; s < 4; s++)
                pb[s] = *(const uint4*)(bbase + (size_t)(32 * s) * Mdim + k0 + 32);
#pragma unroll
            for (int s = 0; s < 4; s++) {
                const float* ar = abase + (size_t)(k0 + 32 + 8 * s) * Ndim;
#pragma unroll
                for (int e = 0; e < 4; e++) pav[s][e] = ar[32 * e];
            }
        }
        // B-operand frags (A^T): 4 n-positions
        bf16x8 bh[4], bl[4];
#pragma unroll
        for (int fj = 0; fj < 4; fj++) {
            int nc = wn + fj * 16 + lm;
            unsigned pp[8];
            *(uint4*)&pp[0] = *(const uint4*)&ap[nc][quad * 8];
            *(uint4*)&pp[4] = *(const uint4*)&ap[nc][quad * 8 + 4];
            unpack8(pp, bh[fj], bl[fj]);
        }
#pragma unroll
        for (int fi = 0; fi < 4; fi++) {
            int rr = wr + fi * 16 + lm;
            unsigned pp[8];
            *(uint4*)&pp[0] = *(const uint4*)&zb[rr][quad * 8];
            *(uint4*)&pp[4] = *(const uint4*)&zb[rr][quad * 8 + 4];
            bf16x8 zh, zl;
            unpack8(pp, zh, zl);
#pragma unroll
            for (int fj = 0; fj < 4; fj++) {
                acc[fi][fj] = __builtin_amdgcn_mfma_f32_16x16x32_bf16(zh, bh[fj], acc[fi][fj], 0, 0, 0);
                acc[fi][fj] = __builtin_amdgcn_mfma_f32_16x16x32_bf16(zh, bl[fj], acc[fi][fj], 0, 0, 0);
                acc[fi][fj] = __builtin_amdgcn_mfma_f32_16x16x32_bf16(zl, bh[fj], acc[fi][fj], 0, 0, 0);
            }
        }
    }
#pragma unroll
    for (int fi = 0; fi < 4; fi++)
#pragma unroll
        for (int fj = 0; fj < 4; fj++)
#pragma unroll
            for (int r = 0; r < 4; r++) {
                int row = r0 + wr + fi * 16 + quad * 4 + r;
                int col = n0 + wn + fj * 16 + lm;
                c[(size_t)row * Ndim + col] = acc[fi][fj][r];
            }
}

// ---------------------------------------------------------------------------
// Fused per-row: u = x - gamma*c; exact 50th-largest |u| (radix select);
// soft-threshold + overshoot; write x; write packed-split z in place of c.
// ---------------------------------------------------------------------------
__global__ __launch_bounds__(256) void topk_update_kernel(
    float* __restrict__ uz, float* __restrict__ x,
    const float* __restrict__ gamma, const float* __restrict__ theta,
    const float* __restrict__ a_param, const float* __restrict__ vv,
    const float* __restrict__ vu, int it)
{
    const int row = blockIdx.x;
    const int t   = threadIdx.x;
    float* crow = uz + (size_t)row * Ndim;
    float* xrow = x  + (size_t)row * Ndim;
    const float g = gamma[it];

    float4 c0 = *(const float4*)(crow + 4 * t);
    float4 c1 = *(const float4*)(crow + 4 * t + 1024);
    float4 x0 = *(const float4*)(xrow + 4 * t);
    float4 x1 = *(const float4*)(xrow + 4 * t + 1024);
    float cv[8] = { c0.x, c0.y, c0.z, c0.w, c1.x, c1.y, c1.z, c1.w };
    float xv[8] = { x0.x, x0.y, x0.z, x0.w, x1.x, x1.y, x1.z, x1.w };

    float uvals[8];
    unsigned keys[8];
#pragma unroll
    for (int e = 0; e < 8; e++) {
        uvals[e] = xv[e] - g * cv[e];
        keys[e]  = __float_as_uint(fabsf(uvals[e]));
    }

    __shared__ unsigned bins[256];
    __shared__ unsigned sel[2];

    unsigned prefix = 0;
    unsigned k = Pk;
#pragma unroll
    for (int pass = 0; pass < 4; ++pass) {
        const int shift = 24 - pass * 8;
        bins[t] = 0;
        __syncthreads();
        const unsigned himask = (pass == 0) ? 0u : (0xFFFFFFFFu << (shift + 8));
#pragma unroll
        for (int e = 0; e < 8; e++) {
            if ((keys[e] & himask) == prefix)
                atomicAdd(&bins[(keys[e] >> shift) & 255], 1u);
        }
        __syncthreads();
        if (t < 64) {
            const int i0 = 255 - 4 * t;
            unsigned c0b = bins[i0], c1b = bins[i0 - 1];
            unsigned c2b = bins[i0 - 2], c3b = bins[i0 - 3];
            unsigned s = c0b + c1b + c2b + c3b;
            unsigned sc = s;
#pragma unroll
            for (int off = 1; off < 64; off <<= 1) {
                unsigned o = __shfl_up(sc, (unsigned)off);
                if (t >= off) sc += o;
            }
            unsigned pre = sc - s;
            unsigned cs[4] = { c0b, c1b, c2b, c3b };
#pragma unroll
            for (int j = 0; j < 4; j++) {
                unsigned cb = cs[j];
                if (pre < k && pre + cb >= k) { sel[0] = (unsigned)(i0 - j); sel[1] = k - pre; }
                pre += cb;
            }
        }
        __syncthreads();
        prefix |= sel[0] << shift;
        k = sel[1];
    }
    const float thresh = __uint_as_float(prefix);

    const float th = theta[it];
    const float ap = a_param[it];
    const bool haveNext = (it + 1) < Kit;
    float tn = 0.f, vn = 0.f, vun = 0.f;
    if (haveNext) { tn = theta[it + 1]; vn = vv[it + 1]; vun = vu[it + 1]; }

    float xo[8];
    unsigned zo[8];
#pragma unroll
    for (int e = 0; e < 8; e++) {
        float uval = uvals[e];
        float au   = fabsf(uval);
        bool keep  = au > thresh;
        float shr  = copysignf(fmaxf(au - th, 0.f), uval);
        float xn   = keep ? uval : shr;
        float d    = xn - xv[e];
        float ov   = 1.f + ap / (fabsf(d) + EPSv);
        float xr   = xv[e] + ov * d;
        xo[e] = xr;
        float z = (1.f + tn * vun * __expf(-vn * fabsf(xr))) * xr;
        zo[e] = packsplit(z);
    }
    float4 a0 = { xo[0], xo[1], xo[2], xo[3] };
    float4 a1 = { xo[4], xo[5], xo[6], xo[7] };
    *(float4*)(xrow + 4 * t) = a0;
    *(float4*)(xrow + 4 * t + 1024) = a1;
    if (haveNext) {
        uint4 z0 = { zo[0], zo[1], zo[2], zo[3] };
        uint4 z1 = { zo[4], zo[5], zo[6], zo[7] };
        *(uint4*)((unsigned*)crow + 4 * t) = z0;
        *(uint4*)((unsigned*)crow + 4 * t + 1024) = z1;
    }
}

// ---------------------------------------------------------------------------
extern "C" void kernel_launch(void* const* d_in, const int* in_sizes, int n_in,
                              void* d_out, int out_size, void* d_ws, size_t ws_size,
                              hipStream_t stream) {
    const float* y       = (const float*)d_in[0];   // (B,M)
    const float* A       = (const float*)d_in[1];   // (M,N)
    const float* gamma   = (const float*)d_in[2];
    const float* theta   = (const float*)d_in[3];
    const float* a_param = (const float*)d_in[4];
    const float* v       = (const float*)d_in[5];
    const float* vu      = (const float*)d_in[6];
    // d_in[7] theta_init (unused: multiplies x==0), d_in[8] info (unused)

    float*    x   = (float*)d_out;                          // (B,N) + 2K zeros
    float*    uz  = (float*)d_ws;                           // (B,N): c fp32 / z packed
    unsigned* bpk = (unsigned*)((char*)d_ws + (size_t)Bsz * Ndim * 4);  // (B,M) packed

    hipMemsetAsync(d_out, 0, (size_t)out_size * sizeof(float), stream);

    dim3 blk(256);
    dim3 g1(Mdim / 64, Bsz / 128);
    dim3 g2(Ndim / 128, Bsz / 128);

    split_negy_kernel<<<(Bsz * Mdim / 4) / 256, blk, 0, stream>>>(y, bpk);

    for (int it = 0; it < Kit; ++it) {
        if (it > 0)
            gemm1_mfma<<<g1, blk, 0, stream>>>((const unsigned*)uz, A, y, bpk);
        gemm2_mfma<<<g2, blk, 0, stream>>>(bpk, A, uz);
        topk_update_kernel<<<Bsz, blk, 0, stream>>>(uz, x, gamma, theta, a_param, v, vu, it);
    }
}

// Round 4
// 4565.077 us; speedup vs baseline: 1.7604x; 1.0635x over previous
//
#include <hip/hip_runtime.h>
#include <math.h>

#define Bsz  8192
#define Mdim 512
#define Ndim 2048
#define Kit  16
#define Pk   50
#define EPSv 0.01f

typedef __attribute__((ext_vector_type(8))) short bf16x8;
typedef __attribute__((ext_vector_type(4))) float f32x4;

// ---- bf16 split helpers: x = h + l to ~2^-16 rel ---------------------------
static __device__ __forceinline__ unsigned short f2bf(float f) {
    unsigned u = __float_as_uint(f);
    return (unsigned short)((u + 0x7fffu + ((u >> 16) & 1u)) >> 16);  // RNE
}
static __device__ __forceinline__ float bf2f(unsigned short h) {
    return __uint_as_float(((unsigned)h) << 16);
}
static __device__ __forceinline__ unsigned packsplit(float x) {
    unsigned short h = f2bf(x);
    float l = x - bf2f(h);          // exact in fp32
    unsigned short lo = f2bf(l);
    return (unsigned)h | ((unsigned)lo << 16);
}

// ---------------------------------------------------------------------------
// One-time: split A into bf16 planes Ah/Al [m][n] and AhT/AlT [n][m].
// ---------------------------------------------------------------------------
__global__ __launch_bounds__(256) void presplit_A(
    const float* __restrict__ A, unsigned short* __restrict__ Ah,
    unsigned short* __restrict__ Al, unsigned short* __restrict__ AhT,
    unsigned short* __restrict__ AlT)
{
    int idx = blockIdx.x * 256 + threadIdx.x;      // 0 .. M*N-1
    int m = idx >> 11, n = idx & (Ndim - 1);
    float a = A[idx];
    unsigned short h = f2bf(a);
    unsigned short l = f2bf(a - bf2f(h));
    Ah[idx] = h; Al[idx] = l;
    AhT[(size_t)n * Mdim + m] = h;
    AlT[(size_t)n * Mdim + m] = l;
}

// ---------------------------------------------------------------------------
// it=0: b = -y, stored packed-split.
// ---------------------------------------------------------------------------
__global__ __launch_bounds__(256) void split_negy_kernel(const float* __restrict__ y,
                                                         unsigned* __restrict__ bpk) {
    int i = blockIdx.x * 256 + threadIdx.x;            // float4 index
    float4 v = ((const float4*)y)[i];
    uint4 o = { packsplit(-v.x), packsplit(-v.y), packsplit(-v.z), packsplit(-v.w) };
    ((uint4*)bpk)[i] = o;
}

// ---------------------------------------------------------------------------
// GEMM1 (NT): b[r][m] = sum_n z[r][n]*A[m][n] - y[r][m], output packed-split.
// z packed (B,N); A from pre-split planes. Tile 128(r)x64(m), BK=64,
// h/l planes in LDS so inner loop has zero unpack VALU.
// ---------------------------------------------------------------------------
__global__ __launch_bounds__(256) void gemm1_mfma(
    const unsigned* __restrict__ zpk,
    const unsigned short* __restrict__ Ah, const unsigned short* __restrict__ Al,
    const float* __restrict__ y, unsigned* __restrict__ bpk)
{
    const int tid  = threadIdx.x;
    const int lane = tid & 63, wid = tid >> 6;
    const int lm   = lane & 15, quad = lane >> 4;
    const int wr   = (wid & 1) * 64, wm = (wid >> 1) * 32;
    const int m0   = blockIdx.x * 64, r0 = blockIdx.y * 128;

    __shared__ unsigned short zh[128][72], zl[128][72];   // [row][k] bf16
    __shared__ unsigned short ah[64][72],  al[64][72];    // [m][k]   bf16

    f32x4 acc[4][2];
#pragma unroll
    for (int i = 0; i < 4; i++)
#pragma unroll
        for (int j = 0; j < 2; j++) acc[i][j] = (f32x4)0.f;

    // z staging: row = tid>>1, thread covers uint4 idx j0..j0+7 (16/row)
    const int zrow = tid >> 1, zj0 = (tid & 1) * 8;
    const unsigned* zbase = zpk + (size_t)(r0 + zrow) * Ndim + zj0 * 4;
    // A staging: row = tid>>2, thread covers uint4 idx a0..a0+1 (8/row of bf16)
    const int arow = tid >> 2, aj0 = (tid & 3) * 2;
    const unsigned short* ahb = Ah + (size_t)(m0 + arow) * Ndim + aj0 * 8;
    const unsigned short* alb = Al + (size_t)(m0 + arow) * Ndim + aj0 * 8;

    uint4 pz[8], pah[2], pal[2];
#pragma unroll
    for (int s = 0; s < 8; s++) pz[s] = *(const uint4*)(zbase + s * 4);
#pragma unroll
    for (int s = 0; s < 2; s++) {
        pah[s] = *(const uint4*)(ahb + s * 8);
        pal[s] = *(const uint4*)(alb + s * 8);
    }

    for (int k0 = 0; k0 < Ndim; k0 += 64) {
        __syncthreads();
#pragma unroll
        for (int s = 0; s < 8; s++) {
            uint4 p = pz[s];
            unsigned hw0 = (p.y << 16) | (p.x & 0xffffu);
            unsigned hw1 = (p.w << 16) | (p.z & 0xffffu);
            unsigned lw0 = (p.x >> 16) | (p.y & 0xffff0000u);
            unsigned lw1 = (p.z >> 16) | (p.w & 0xffff0000u);
            int col = (zj0 + s) * 4;
            uint2 hh = { hw0, hw1 }, ll = { lw0, lw1 };
            *(uint2*)&zh[zrow][col] = hh;
            *(uint2*)&zl[zrow][col] = ll;
        }
#pragma unroll
        for (int s = 0; s < 2; s++) {
            *(uint4*)&ah[arow][(aj0 + s) * 8] = pah[s];
            *(uint4*)&al[arow][(aj0 + s) * 8] = pal[s];
        }
        __syncthreads();
        if (k0 + 64 < Ndim) {
#pragma unroll
            for (int s = 0; s < 8; s++)
                pz[s] = *(const uint4*)(zbase + s * 4 + k0 + 64);
#pragma unroll
            for (int s = 0; s < 2; s++) {
                pah[s] = *(const uint4*)(ahb + s * 8 + k0 + 64);
                pal[s] = *(const uint4*)(alb + s * 8 + k0 + 64);
            }
        }
#pragma unroll
        for (int kk = 0; kk < 2; kk++) {
            const int ko = kk * 32 + quad * 8;
            bf16x8 bhf[2], blf[2];
#pragma unroll
            for (int fj = 0; fj < 2; fj++) {
                bhf[fj] = *(const bf16x8*)&ah[wm + fj * 16 + lm][ko];
                blf[fj] = *(const bf16x8*)&al[wm + fj * 16 + lm][ko];
            }
#pragma unroll
            for (int fi = 0; fi < 4; fi++) {
                bf16x8 zh8 = *(const bf16x8*)&zh[wr + fi * 16 + lm][ko];
                bf16x8 zl8 = *(const bf16x8*)&zl[wr + fi * 16 + lm][ko];
#pragma unroll
                for (int fj = 0; fj < 2; fj++) {
                    acc[fi][fj] = __builtin_amdgcn_mfma_f32_16x16x32_bf16(zh8, bhf[fj], acc[fi][fj], 0, 0, 0);
                    acc[fi][fj] = __builtin_amdgcn_mfma_f32_16x16x32_bf16(zh8, blf[fj], acc[fi][fj], 0, 0, 0);
                    acc[fi][fj] = __builtin_amdgcn_mfma_f32_16x16x32_bf16(zl8, bhf[fj], acc[fi][fj], 0, 0, 0);
                }
            }
        }
    }
    // epilogue: subtract y, split, store packed.  D: col=lane&15, row=quad*4+r
#pragma unroll
    for (int fi = 0; fi < 4; fi++)
#pragma unroll
        for (int fj = 0; fj < 2; fj++)
#pragma unroll
            for (int r = 0; r < 4; r++) {
                int row = r0 + wr + fi * 16 + quad * 4 + r;
                int col = m0 + wm + fj * 16 + lm;
                float bv = acc[fi][fj][r] - y[(size_t)row * Mdim + col];
                bpk[(size_t)row * Mdim + col] = packsplit(bv);
            }
}

// ---------------------------------------------------------------------------
// GEMM2 (NN): c[r][n] = sum_m b[r][m]*A[m][n], c fp32. b packed (B,M);
// A from pre-split transposed planes AhT/AlT [n][m]. Tile 128x128, BK=32.
// ---------------------------------------------------------------------------
__global__ __launch_bounds__(256) void gemm2_mfma(
    const unsigned* __restrict__ bpk,
    const unsigned short* __restrict__ AhT, const unsigned short* __restrict__ AlT,
    float* __restrict__ c)
{
    const int tid  = threadIdx.x;
    const int lane = tid & 63, wid = tid >> 6;
    const int lm   = lane & 15, quad = lane >> 4;
    const int wr   = (wid & 1) * 64, wn = (wid >> 1) * 64;
    const int n0   = blockIdx.x * 128, r0 = blockIdx.y * 128;

    __shared__ unsigned short bh[128][40], bl[128][40];   // [row][k=m]
    __shared__ unsigned short ath[128][40], atl[128][40]; // [n][k=m]

    f32x4 acc[4][4];
#pragma unroll
    for (int i = 0; i < 4; i++)
#pragma unroll
        for (int j = 0; j < 4; j++) acc[i][j] = (f32x4)0.f;

    // b staging: row = tid>>1, uint4 idx j0..j0+3 (8/row)
    const int brow = tid >> 1, bj0 = (tid & 1) * 4;
    const unsigned* bbase = bpk + (size_t)(r0 + brow) * Mdim + bj0 * 4;
    // A staging: row = tid>>1, plane = tid&1; 4 uint4 per row-plane
    const int arow = tid >> 1, apl = tid & 1;
    const unsigned short* abase = (apl ? AlT : AhT) + (size_t)(n0 + arow) * Mdim;

    uint4 pb[4], pa[4];
#pragma unroll
    for (int s = 0; s < 4; s++) pb[s] = *(const uint4*)(bbase + s * 4);
#pragma unroll
    for (int s = 0; s < 4; s++) pa[s] = *(const uint4*)(abase + s * 8);

    for (int k0 = 0; k0 < Mdim; k0 += 32) {
        __syncthreads();
#pragma unroll
        for (int s = 0; s < 4; s++) {
            uint4 p = pb[s];
            unsigned hw0 = (p.y << 16) | (p.x & 0xffffu);
            unsigned hw1 = (p.w << 16) | (p.z & 0xffffu);
            unsigned lw0 = (p.x >> 16) | (p.y & 0xffff0000u);
            unsigned lw1 = (p.z >> 16) | (p.w & 0xffff0000u);
            int col = (bj0 + s) * 4;
            uint2 hh = { hw0, hw1 }, ll = { lw0, lw1 };
            *(uint2*)&bh[brow][col] = hh;
            *(uint2*)&bl[brow][col] = ll;
        }
        {
            unsigned short (*dst)[40] = apl ? atl : ath;
#pragma unroll
            for (int s = 0; s < 4; s++) *(uint4*)&dst[arow][s * 8] = pa[s];
        }
        __syncthreads();
        if (k0 + 32 < Mdim) {
#pragma unroll
            for (int s = 0; s < 4; s++)
                pb[s] = *(const uint4*)(bbase + s * 4 + k0 + 32);
#pragma unroll
            for (int s = 0; s < 4; s++)
                pa[s] = *(const uint4*)(abase + s * 8 + k0 + 32);
        }
        const int ko = quad * 8;
        bf16x8 ahf[4], alf[4];
#pragma unroll
        for (int fj = 0; fj < 4; fj++) {
            ahf[fj] = *(const bf16x8*)&ath[wn + fj * 16 + lm][ko];
            alf[fj] = *(const bf16x8*)&atl[wn + fj * 16 + lm][ko];
        }
#pragma unroll
        for (int fi = 0; fi < 4; fi++) {
            bf16x8 bh8 = *(const bf16x8*)&bh[wr + fi * 16 + lm][ko];
            bf16x8 bl8 = *(const bf16x8*)&bl[wr + fi * 16 + lm][ko];
#pragma unroll
            for (int fj = 0; fj < 4; fj++) {
                acc[fi][fj] = __builtin_amdgcn_mfma_f32_16x16x32_bf16(bh8, ahf[fj], acc[fi][fj], 0, 0, 0);
                acc[fi][fj] = __builtin_amdgcn_mfma_f32_16x16x32_bf16(bh8, alf[fj], acc[fi][fj], 0, 0, 0);
                acc[fi][fj] = __builtin_amdgcn_mfma_f32_16x16x32_bf16(bl8, ahf[fj], acc[fi][fj], 0, 0, 0);
            }
        }
    }
#pragma unroll
    for (int fi = 0; fi < 4; fi++)
#pragma unroll
        for (int fj = 0; fj < 4; fj++)
#pragma unroll
            for (int r = 0; r < 4; r++) {
                int row = r0 + wr + fi * 16 + quad * 4 + r;
                int col = n0 + wn + fj * 16 + lm;
                c[(size_t)row * Ndim + col] = acc[fi][fj][r];
            }
}

// ---------------------------------------------------------------------------
// Fused per-row: u = x - gamma*c; exact 50th-largest |u| (radix select);
// soft-threshold + overshoot; write x; write packed-split z in place of c.
// ---------------------------------------------------------------------------
__global__ __launch_bounds__(256) void topk_update_kernel(
    float* __restrict__ uz, float* __restrict__ x,
    const float* __restrict__ gamma, const float* __restrict__ theta,
    const float* __restrict__ a_param, const float* __restrict__ vv,
    const float* __restrict__ vu, int it)
{
    const int row = blockIdx.x;
    const int t   = threadIdx.x;
    float* crow = uz + (size_t)row * Ndim;
    float* xrow = x  + (size_t)row * Ndim;
    const float g = gamma[it];

    float4 c0 = *(const float4*)(crow + 4 * t);
    float4 c1 = *(const float4*)(crow + 4 * t + 1024);
    float4 x0 = *(const float4*)(xrow + 4 * t);
    float4 x1 = *(const float4*)(xrow + 4 * t + 1024);
    float cv[8] = { c0.x, c0.y, c0.z, c0.w, c1.x, c1.y, c1.z, c1.w };
    float xv[8] = { x0.x, x0.y, x0.z, x0.w, x1.x, x1.y, x1.z, x1.w };

    float uvals[8];
    unsigned keys[8];
#pragma unroll
    for (int e = 0; e < 8; e++) {
        uvals[e] = xv[e] - g * cv[e];
        keys[e]  = __float_as_uint(fabsf(uvals[e]));
    }

    __shared__ unsigned bins[256];
    __shared__ unsigned sel[2];

    unsigned prefix = 0;
    unsigned k = Pk;
#pragma unroll
    for (int pass = 0; pass < 4; ++pass) {
        const int shift = 24 - pass * 8;
        bins[t] = 0;
        __syncthreads();
        const unsigned himask = (pass == 0) ? 0u : (0xFFFFFFFFu << (shift + 8));
#pragma unroll
        for (int e = 0; e < 8; e++) {
            if ((keys[e] & himask) == prefix)
                atomicAdd(&bins[(keys[e] >> shift) & 255], 1u);
        }
        __syncthreads();
        if (t < 64) {
            const int i0 = 255 - 4 * t;
            unsigned c0b = bins[i0], c1b = bins[i0 - 1];
            unsigned c2b = bins[i0 - 2], c3b = bins[i0 - 3];
            unsigned s = c0b + c1b + c2b + c3b;
            unsigned sc = s;
#pragma unroll
            for (int off = 1; off < 64; off <<= 1) {
                unsigned o = __shfl_up(sc, (unsigned)off);
                if (t >= off) sc += o;
            }
            unsigned pre = sc - s;
            unsigned cs[4] = { c0b, c1b, c2b, c3b };
#pragma unroll
            for (int j = 0; j < 4; j++) {
                unsigned cb = cs[j];
                if (pre < k && pre + cb >= k) { sel[0] = (unsigned)(i0 - j); sel[1] = k - pre; }
                pre += cb;
            }
        }
        __syncthreads();
        prefix |= sel[0] << shift;
        k = sel[1];
    }
    const float thresh = __uint_as_float(prefix);

    const float th = theta[it];
    const float ap = a_param[it];
    const bool haveNext = (it + 1) < Kit;
    float tn = 0.f, vn = 0.f, vun = 0.f;
    if (haveNext) { tn = theta[it + 1]; vn = vv[it + 1]; vun = vu[it + 1]; }

    float xo[8];
    unsigned zo[8];
#pragma unroll
    for (int e = 0; e < 8; e++) {
        float uval = uvals[e];
        float au   = fabsf(uval);
        bool keep  = au > thresh;
        float shr  = copysignf(fmaxf(au - th, 0.f), uval);
        float xn   = keep ? uval : shr;
        float d    = xn - xv[e];
        float ov   = 1.f + ap / (fabsf(d) + EPSv);
        float xr   = xv[e] + ov * d;
        xo[e] = xr;
        float z = (1.f + tn * vun * __expf(-vn * fabsf(xr))) * xr;
        zo[e] = packsplit(z);
    }
    float4 a0 = { xo[0], xo[1], xo[2], xo[3] };
    float4 a1 = { xo[4], xo[5], xo[6], xo[7] };
    *(float4*)(xrow + 4 * t) = a0;
    *(float4*)(xrow + 4 * t + 1024) = a1;
    if (haveNext) {
        uint4 z0 = { zo[0], zo[1], zo[2], zo[3] };
        uint4 z1 = { zo[4], zo[5], zo[6], zo[7] };
        *(uint4*)((unsigned*)crow + 4 * t) = z0;
        *(uint4*)((unsigned*)crow + 4 * t + 1024) = z1;
    }
}

// ---------------------------------------------------------------------------
extern "C" void kernel_launch(void* const* d_in, const int* in_sizes, int n_in,
                              void* d_out, int out_size, void* d_ws, size_t ws_size,
                              hipStream_t stream) {
    const float* y       = (const float*)d_in[0];   // (B,M)
    const float* A       = (const float*)d_in[1];   // (M,N)
    const float* gamma   = (const float*)d_in[2];
    const float* theta   = (const float*)d_in[3];
    const float* a_param = (const float*)d_in[4];
    const float* v       = (const float*)d_in[5];
    const float* vu      = (const float*)d_in[6];
    // d_in[7] theta_init (unused: multiplies x==0), d_in[8] info (unused)

    float* x = (float*)d_out;                       // (B,N) + 2K zeros

    // workspace layout (88 MB total)
    char* ws = (char*)d_ws;
    float*          uz  = (float*)ws;                                   // 64 MB: c fp32 / z packed
    unsigned*       bpk = (unsigned*)(ws + (size_t)Bsz * Ndim * 4);     // 16 MB: b packed
    unsigned short* Ah  = (unsigned short*)(ws + (size_t)80 * 1024 * 1024);
    unsigned short* Al  = Ah  + (size_t)Mdim * Ndim;                    // 2 MB each
    unsigned short* AhT = Al  + (size_t)Mdim * Ndim;
    unsigned short* AlT = AhT + (size_t)Mdim * Ndim;

    hipMemsetAsync(d_out, 0, (size_t)out_size * sizeof(float), stream);

    dim3 blk(256);
    dim3 g1(Mdim / 64, Bsz / 128);
    dim3 g2(Ndim / 128, Bsz / 128);

    presplit_A<<<(Mdim * Ndim) / 256, blk, 0, stream>>>(A, Ah, Al, AhT, AlT);
    split_negy_kernel<<<(Bsz * Mdim / 4) / 256, blk, 0, stream>>>(y, bpk);

    for (int it = 0; it < Kit; ++it) {
        if (it > 0)
            gemm1_mfma<<<g1, blk, 0, stream>>>((const unsigned*)uz, Ah, Al, y, bpk);
        gemm2_mfma<<<g2, blk, 0, stream>>>(bpk, AhT, AlT, uz);
        topk_update_kernel<<<Bsz, blk, 0, stream>>>(uz, x, gamma, theta, a_param, v, vu, it);
    }
}